// Round 1
// baseline (907.683 us; speedup 1.0000x reference)
//
#include <hip/hip_runtime.h>
#include <math.h>

#define B 16
#define C 384
#define CPAD 385
#define H 96
#define W 96
#define HW (H*W)
#define M 2048
#define K2 49
#define RAD 3
#define NSEL 512
#define INV_TAU 10.0f
#define TP 32            // pixels per transpose tile

__device__ inline float wave_max(float v){
  #pragma unroll
  for (int o = 32; o; o >>= 1) v = fmaxf(v, __shfl_xor(v, o));
  return v;
}
__device__ inline float wave_sum(float v){
  #pragma unroll
  for (int o = 32; o; o >>= 1) v += __shfl_xor(v, o);
  return v;
}

// Coalesced lane-interleaved dot: lane l owns channels {2l,2l+1}+128j, j=0..2.
// Each float2 load instruction is 512 B contiguous across the wave (8 lines
// vs 24 for the old lane*6 layout). Full-wave butterfly gives the dot sum.
__device__ inline float dot_wave(float2 c0, float2 c1, float2 c2,
                                 const float2* __restrict__ nb2){
  float2 n0 = nb2[0], n1 = nb2[64], n2 = nb2[128];
  float acc = c0.x * n0.x;
  acc = fmaf(c0.y, n0.y, acc);
  acc = fmaf(c1.x, n1.x, acc); acc = fmaf(c1.y, n1.y, acc);
  acc = fmaf(c2.x, n2.x, acc); acc = fmaf(c2.y, n2.y, acc);
  acc += __shfl_xor(acc, 32); acc += __shfl_xor(acc, 16);
  acc += __shfl_xor(acc, 8);  acc += __shfl_xor(acc, 4);
  acc += __shfl_xor(acc, 2);  acc += __shfl_xor(acc, 1);
  return acc;
}

// ---------------- fast path: pixel-major layout ----------------

// Transpose [C, HW-tile] -> [pix, C], normalizing each pixel's channel vector.
__global__ void tnorm_kernel(const float* __restrict__ src, float* __restrict__ dst){
  int blk = blockIdx.x;                 // B * (HW/TP)
  int b = blk / (HW / TP);
  int pixbase = (blk % (HW / TP)) * TP;
  __shared__ float tile[TP][CPAD];      // +1 pad: conflict-free col writes
  __shared__ float scale[TP];
  const float* sb = src + (size_t)b * C * HW + pixbase;
  int tx = threadIdx.x & 31;            // pixel in tile
  int ty = threadIdx.x >> 5;            // channel slice 0..7
  #pragma unroll 4
  for (int c0 = 0; c0 < C; c0 += 8){
    tile[tx][c0 + ty] = sb[(size_t)(c0 + ty) * HW + tx];
  }
  __syncthreads();
  // per-pixel sum of squares: 8 consecutive lanes per pixel
  int pix = threadIdx.x >> 3;
  int j = threadIdx.x & 7;
  float ss = 0.f;
  #pragma unroll 4
  for (int c = j * 48; c < j * 48 + 48; ++c){ float v = tile[pix][c]; ss = fmaf(v, v, ss); }
  ss += __shfl_xor(ss, 1); ss += __shfl_xor(ss, 2); ss += __shfl_xor(ss, 4);
  if (j == 0) scale[pix] = 1.0f / fmaxf(sqrtf(ss), 1e-12f);
  __syncthreads();
  // vectorized float4 store: fewer instructions on an HBM-bound kernel
  float4* db4 = (float4*)(dst + ((size_t)b * HW + pixbase) * C);
  #pragma unroll 4
  for (int l = threadIdx.x; l < TP * (C / 4); l += 256){
    int p = l / (C / 4), c4 = l - p * (C / 4);
    float s = scale[p];
    float4 v;
    v.x = tile[p][c4 * 4 + 0] * s;
    v.y = tile[p][c4 * 4 + 1] * s;
    v.z = tile[p][c4 * 4 + 2] * s;
    v.w = tile[p][c4 * 4 + 3] * s;
    db4[(size_t)p * (C / 4) + c4] = v;
  }
}

// 4 waves per 256-thread block (occupancy: up to 32 waves/CU vs 16 with
// 1-wave blocks). One wave per (b, candidate): 49 coalesced length-384 dots;
// softmax+entropy via shuffles; sims cached for the KL phase.
__global__ __launch_bounds__(256) void cand2_kernel(const float* __restrict__ fT,
                             const int* __restrict__ anch,
                             float* __restrict__ simc, float* __restrict__ ent){
  int bm = blockIdx.x * 4 + (threadIdx.x >> 6);
  int b = bm >> 11, m = bm & (M - 1);
  int lane = threadIdx.x & 63;
  int ay = anch[2 * m], ax = anch[2 * m + 1];
  const float* img = fT + (size_t)b * HW * C;
  const float2* ctr2 = (const float2*)(img + (size_t)(ay * W + ax) * C) + lane;
  float2 c0 = ctr2[0], c1 = ctr2[64], c2 = ctr2[128];
  float mysim = 0.f;
  int k = 0;
  for (int dy = -RAD; dy <= RAD; ++dy){
    const float* rowp = img + (size_t)((ay + dy) * W + (ax - RAD)) * C;
    #pragma unroll
    for (int dx = 0; dx < 7; ++dx){
      const float2* nb2 = (const float2*)(rowp + (size_t)dx * C) + lane;
      float acc = dot_wave(c0, c1, c2, nb2);
      if (lane == k) mysim = acc;
      ++k;
    }
  }
  mysim *= INV_TAU;
  float v = (lane < K2) ? mysim : -INFINITY;
  float mx = wave_max(v);
  float e = (lane < K2) ? expf(mysim - mx) : 0.f;
  float se = wave_sum(e);
  float p = e / se;
  float term = (lane < K2) ? (-p * logf(p + 1e-6f)) : 0.f;
  float en = wave_sum(term);
  if (lane == 0) ent[bm] = en;
  if (lane < K2) simc[(size_t)bm * K2 + lane] = mysim;
}

// Exact top-512-smallest-entropy per image via lexicographic rank counting
// (matches jax.lax.top_k tie-breaking; ranks unique -> perfect compaction).
__global__ void select_kernel(const float* __restrict__ ent, int* __restrict__ sel){
  int blk = blockIdx.x;                 // B*8 blocks
  int b = blk >> 3;
  int i = (blk & 7) * 256 + threadIdx.x;
  __shared__ float se[M];
  for (int j = threadIdx.x; j < M; j += 256) se[j] = ent[b * M + j];
  __syncthreads();
  float ei = se[i];
  int r = 0;
  for (int j = 0; j < M; ++j){
    float ej = se[j];
    r += (ej < ei) || (ej == ei && j < i);
  }
  if (r < NSEL) sel[b * NSEL + r] = i;
}

// 4 waves per block; one wave per (b, selected anchor): student sims from
// normalized pixel-major student; teacher sims from cache; dual log-softmax
// + KL; per-wave partial.
__global__ __launch_bounds__(256) void kl2_kernel(const float* __restrict__ fS,
                           const int* __restrict__ anch,
                           const float* __restrict__ simc, const int* __restrict__ sel,
                           float* __restrict__ klpart){
  int bj = blockIdx.x * 4 + (threadIdx.x >> 6);
  int b = bj >> 9, j = bj & (NSEL - 1);
  int lane = threadIdx.x & 63;
  int m = sel[b * NSEL + j];
  int ay = anch[2 * m], ax = anch[2 * m + 1];
  const float* img = fS + (size_t)b * HW * C;
  const float2* ctr2 = (const float2*)(img + (size_t)(ay * W + ax) * C) + lane;
  float2 c0 = ctr2[0], c1 = ctr2[64], c2 = ctr2[128];
  float mysim = 0.f;
  int k = 0;
  for (int dy = -RAD; dy <= RAD; ++dy){
    const float* rowp = img + (size_t)((ay + dy) * W + (ax - RAD)) * C;
    #pragma unroll
    for (int dx = 0; dx < 7; ++dx){
      const float2* nb2 = (const float2*)(rowp + (size_t)dx * C) + lane;
      float acc = dot_wave(c0, c1, c2, nb2);
      if (lane == k) mysim = acc;
      ++k;
    }
  }
  float sim_sv = mysim * INV_TAU;
  float sim_tv = (lane < K2) ? simc[((size_t)b * M + m) * K2 + lane] : -INFINITY;

  float vs = (lane < K2) ? sim_sv : -INFINITY;
  float mxs = wave_max(vs);
  float es = (lane < K2) ? expf(sim_sv - mxs) : 0.f;
  float sums = wave_sum(es);
  float ls = sim_sv - mxs - logf(sums);

  float mxt = wave_max(sim_tv);
  float et = (lane < K2) ? expf(sim_tv - mxt) : 0.f;
  float sumt = wave_sum(et);
  float lt = sim_tv - mxt - logf(sumt);

  float pt = et / sumt;
  float term = (lane < K2) ? pt * (lt - ls) : 0.f;
  float kl = wave_sum(term);
  if (lane == 0) klpart[bj] = kl;
}

__global__ void reduce_kernel(const float* __restrict__ part, float* __restrict__ out){
  float s = 0.f;
  for (int i = threadIdx.x; i < B * NSEL; i += 256) s += part[i];
  s = wave_sum(s);
  __shared__ float wsum[4];
  if ((threadIdx.x & 63) == 0) wsum[threadIdx.x >> 6] = s;
  __syncthreads();
  if (threadIdx.x == 0) out[0] = (wsum[0] + wsum[1] + wsum[2] + wsum[3]) * (1.0f / (B * NSEL));
}

// ---------------- fallback path (round-1, ~13 MB ws) ----------------

__global__ void norms_kernel(const float* __restrict__ t, const float* __restrict__ s,
                             float* __restrict__ inv_t, float* __restrict__ inv_s){
  int pix = blockIdx.x * blockDim.x + threadIdx.x;
  if (pix >= B * HW) return;
  int b = pix / HW, p = pix - b * HW;
  const float* tb = t + (size_t)b * C * HW + p;
  const float* sb = s + (size_t)b * C * HW + p;
  float at = 0.f, as = 0.f;
  #pragma unroll 4
  for (int c = 0; c < C; ++c){
    float v = tb[(size_t)c * HW]; at = fmaf(v, v, at);
    float u = sb[(size_t)c * HW]; as = fmaf(u, u, as);
  }
  inv_t[pix] = 1.0f / fmaxf(sqrtf(at), 1e-12f);
  inv_s[pix] = 1.0f / fmaxf(sqrtf(as), 1e-12f);
}

__global__ void cand_kernel(const float* __restrict__ t, const int* __restrict__ anch,
                            const float* __restrict__ inv_t,
                            float* __restrict__ simc, float* __restrict__ ent){
  int bm = blockIdx.x;
  int b = bm >> 11, m = bm & (M - 1);
  int lane = threadIdx.x;
  int ay = anch[2 * m], ax = anch[2 * m + 1];
  int k = lane < K2 ? lane : 0;
  int dy = k / 7 - RAD, dx = k - (k / 7) * 7 - RAD;
  int pc = ay * W + ax;
  int pk = (ay + dy) * W + (ax + dx);
  const float* base = t + (size_t)b * C * HW;
  float acc = 0.f;
  #pragma unroll 4
  for (int c = 0; c < C; ++c){
    const float* row = base + (size_t)c * HW;
    acc = fmaf(row[pc], row[pk], acc);
  }
  float sim = acc * inv_t[b * HW + pc] * inv_t[b * HW + pk] * INV_TAU;
  float v = (lane < K2) ? sim : -INFINITY;
  float mx = wave_max(v);
  float e = (lane < K2) ? expf(sim - mx) : 0.f;
  float se = wave_sum(e);
  float p = e / se;
  float term = (lane < K2) ? (-p * logf(p + 1e-6f)) : 0.f;
  float en = wave_sum(term);
  if (lane == 0) ent[bm] = en;
  if (lane < K2) simc[(size_t)bm * K2 + lane] = sim;
}

__global__ void kl_kernel(const float* __restrict__ s, const int* __restrict__ anch,
                          const float* __restrict__ inv_s, const float* __restrict__ simc,
                          const int* __restrict__ sel, float* __restrict__ klpart){
  int bj = blockIdx.x;
  int b = bj >> 9, j = bj & (NSEL - 1);
  int lane = threadIdx.x;
  int m = sel[b * NSEL + j];
  int ay = anch[2 * m], ax = anch[2 * m + 1];
  int k = lane < K2 ? lane : 0;
  int dy = k / 7 - RAD, dx = k - (k / 7) * 7 - RAD;
  int pc = ay * W + ax;
  int pk = (ay + dy) * W + (ax + dx);
  const float* base = s + (size_t)b * C * HW;
  float acc = 0.f;
  #pragma unroll 4
  for (int c = 0; c < C; ++c){
    const float* row = base + (size_t)c * HW;
    acc = fmaf(row[pc], row[pk], acc);
  }
  float sim_sv = acc * inv_s[b * HW + pc] * inv_s[b * HW + pk] * INV_TAU;
  float sim_tv = (lane < K2) ? simc[((size_t)b * M + m) * K2 + lane] : -INFINITY;

  float vs = (lane < K2) ? sim_sv : -INFINITY;
  float mxs = wave_max(vs);
  float es = (lane < K2) ? expf(sim_sv - mxs) : 0.f;
  float sums = wave_sum(es);
  float ls = sim_sv - mxs - logf(sums);

  float mxt = wave_max(sim_tv);
  float et = (lane < K2) ? expf(sim_tv - mxt) : 0.f;
  float sumt = wave_sum(et);
  float lt = sim_tv - mxt - logf(sumt);

  float pt = et / sumt;
  float term = (lane < K2) ? pt * (lt - ls) : 0.f;
  float kl = wave_sum(term);
  if (lane == 0) klpart[bj] = kl;
}

extern "C" void kernel_launch(void* const* d_in, const int* in_sizes, int n_in,
                              void* d_out, int out_size, void* d_ws, size_t ws_size,
                              hipStream_t stream){
  const float* student = (const float*)d_in[0];
  const float* teacher = (const float*)d_in[1];
  const int*   anch    = (const int*)d_in[2];
  float* out = (float*)d_out;

  const size_t fbuf_elems = (size_t)B * HW * C;            // 56.6M floats
  const size_t simc_elems = (size_t)B * M * K2;
  size_t req = (fbuf_elems + simc_elems + (size_t)B * M + (size_t)B * NSEL) * sizeof(float)
             + (size_t)B * NSEL * sizeof(int);

  if (ws_size >= req){
    float* fbuf   = (float*)d_ws;                          // reused: teacher then student
    float* simc   = fbuf + fbuf_elems;
    float* ent    = simc + simc_elems;
    float* klpart = ent + (size_t)B * M;
    int*   sel    = (int*)(klpart + (size_t)B * NSEL);

    hipLaunchKernelGGL(tnorm_kernel, dim3(B * (HW / TP)), dim3(256), 0, stream, teacher, fbuf);
    hipLaunchKernelGGL(cand2_kernel, dim3(B * M / 4), dim3(256), 0, stream, fbuf, anch, simc, ent);
    hipLaunchKernelGGL(select_kernel, dim3(B * 8), dim3(256), 0, stream, ent, sel);
    hipLaunchKernelGGL(tnorm_kernel, dim3(B * (HW / TP)), dim3(256), 0, stream, student, fbuf);
    hipLaunchKernelGGL(kl2_kernel, dim3(B * NSEL / 4), dim3(256), 0, stream, fbuf, anch, simc, sel, klpart);
    hipLaunchKernelGGL(reduce_kernel, dim3(1), dim3(256), 0, stream, klpart, out);
  } else {
    float* ws2    = (float*)d_ws;
    float* inv_t  = ws2;
    float* inv_s  = inv_t + B * HW;
    float* ent    = inv_s + B * HW;
    float* simc   = ent + B * M;
    float* klpart = simc + simc_elems;
    int*   sel    = (int*)(klpart + (size_t)B * NSEL);

    hipLaunchKernelGGL(norms_kernel, dim3((B * HW + 255) / 256), dim3(256), 0, stream,
                       teacher, student, inv_t, inv_s);
    hipLaunchKernelGGL(cand_kernel, dim3(B * M), dim3(64), 0, stream,
                       teacher, anch, inv_t, simc, ent);
    hipLaunchKernelGGL(select_kernel, dim3(B * 8), dim3(256), 0, stream, ent, sel);
    hipLaunchKernelGGL(kl_kernel, dim3(B * NSEL), dim3(64), 0, stream,
                       student, anch, inv_s, simc, sel, klpart);
    hipLaunchKernelGGL(reduce_kernel, dim3(1), dim3(256), 0, stream, klpart, out);
  }
}